// Round 5
// baseline (317.212 us; speedup 1.0000x reference)
//
#include <hip/hip_runtime.h>
#include <math.h>

#define A_N 64
#define B_N 4096
#define D_N 50
#define H_N 192
#define O_N 3

typedef __attribute__((ext_vector_type(8))) __bf16 bf16x8;
typedef __attribute__((ext_vector_type(4))) __bf16 bf16x4;
typedef __attribute__((ext_vector_type(4))) float f32x4;

// ws layout (bf16 elems), frag-packed: frag elem (lane,j) = W[nt*16+(lane&15)][ks*32+(lane>>4)*8+j]
#define W1_OFF   0          // [A][12 nt][2 ks][512]   K=64 (padded from 50)
#define S1_OFF   786432
#define W2_OFF   1572864    // [A][12 nt][6 ks][512]   K=192
#define S2_OFF   3932160
#define W3_OFF   6291456
#define OW_OFF   8650752    // [A][6 ks][512]          N=16 (padded from 3), K=192
#define WS_ELEMS 8847360    // *2 B = 17.7 MB of d_ws

#if __has_builtin(__builtin_amdgcn_rcpf)
#define FRCP(x) __builtin_amdgcn_rcpf(x)
#else
#define FRCP(x) (1.0f / (x))
#endif
#if __has_builtin(__builtin_amdgcn_exp2f)
#define FEXP2(x) __builtin_amdgcn_exp2f(x)
#else
#define FEXP2(x) exp2f(x)
#endif

// A&S 7.1.26 erf (|eps|<=1.5e-7) + native rcp/exp2
__device__ __forceinline__ float gelu_f(float xx) {
    float t  = 0.70710678118654752440f * xx;
    float at = fabsf(t);
    float k  = FRCP(fmaf(0.3275911f, at, 1.0f));
    float p  = fmaf(k, 1.061405429f, -1.453152027f);
    p = fmaf(k, p, 1.421413741f);
    p = fmaf(k, p, -0.284496736f);
    p = fmaf(k, p, 0.254829592f);
    p = p * k;
    float e  = FEXP2(t * t * -1.44269504088896340736f);
    float er = fmaf(-p, e, 1.0f);
    er = (t < 0.f) ? -er : er;
    return 0.5f * xx * (1.0f + er);
}

// Prep v3 (HW-validated). Round-1 lesson: prep is ~8 us of BW-bound work; the ~78 us
// total-vs-srek gap is FIXED harness overhead (noisy +-15us). Do NOT delete prep.
__global__ __launch_bounds__(256)
void prep_kernel(const float* __restrict__ w1, const float* __restrict__ s1,
                 const float* __restrict__ w2, const float* __restrict__ s2,
                 const float* __restrict__ w3, const float* __restrict__ ow,
                 __bf16* __restrict__ ws) {
    __shared__ __bf16 T[192 * 72];   // sec A uses [32][200] = 6400 of it
    const int b   = blockIdx.x;
    const int tid = threadIdx.x;

    if (b < 1152) {
        int m  = b / 384;                 // 0=w2 1=s2 2=w3
        int r  = b % 384;
        int a  = r / 6;
        int rc = r % 6;                   // 32-row chunk
        const float* src = ((m == 0) ? w2 : (m == 1) ? s2 : w3) + (size_t)a * 36864;
        __bf16* dst = ws + ((m == 0) ? W2_OFF : (m == 1) ? S2_OFF : W3_OFF) + (size_t)a * 36864;
        #pragma unroll
        for (int i = 0; i < 6; ++i) {                 // 1536 float4 = 32 rows x 192 cols
            int f4 = i * 256 + tid;
            int row = f4 / 48, kc = (f4 % 48) * 4;
            f32x4 v = *(const f32x4*)(src + (size_t)(rc * 32 + row) * 192 + kc);
            bf16x4 o;
            #pragma unroll
            for (int j = 0; j < 4; ++j) o[j] = (__bf16)v[j];
            *(bf16x4*)(T + row * 200 + kc) = o;       // pitch 200: 2-way max
        }
        __syncthreads();
        #pragma unroll
        for (int i = 0; i < 3; ++i) {                 // 768 frag-rows (2 nt x 6 ks x 64)
            int fr = i * 256 + tid;
            int f = fr >> 6, lane = fr & 63;
            int ntl = f / 6, ks = f % 6;
            int n = ntl * 16 + (lane & 15), k = ks * 32 + (lane >> 4) * 8;
            bf16x8 v = *(const bf16x8*)(T + n * 200 + k);
            *(bf16x8*)(dst + ((size_t)(rc * 2 + ntl) * 6 + ks) * 512 + lane * 8) = v;
        }
    } else if (b < 1280) {
        int r = b - 1152; int m = r >> 6; int a = r & 63;
        const float* src = (m ? s1 : w1) + (size_t)a * 9600;
        __bf16* dst = ws + (m ? S1_OFF : W1_OFF) + (size_t)a * 12288;
        for (int e = tid; e < 192 * 72; e += 256) T[e] = (__bf16)0.f;
        __syncthreads();
        for (int e = tid; e < 9600; e += 256) {
            int row = e / 50, k = e - row * 50;
            T[row * 72 + k] = (__bf16)src[e];
        }
        __syncthreads();
        #pragma unroll
        for (int i = 0; i < 6; ++i) {                 // 1536 frag-rows (12 nt x 2 ks x 64)
            int fr = i * 256 + tid;
            int f = fr >> 6, lane = fr & 63;
            int nt = f >> 1, ks = f & 1;
            int n = nt * 16 + (lane & 15), k = ks * 32 + (lane >> 4) * 8;
            bf16x8 v = *(const bf16x8*)(T + n * 72 + k);
            *(bf16x8*)(dst + (size_t)(nt * 2 + ks) * 512 + lane * 8) = v;
        }
    } else {
        int r = b - 1280;
        #pragma unroll
        for (int i = 0; i < 8; ++i) {                 // 24576 frag-rows total
            int fr = (r * 8 + i) * 256 + tid;
            int a = fr / 384, rem = fr - a * 384;
            int ks = rem >> 6, lane = rem & 63;
            int n = lane & 15, k = ks * 32 + (lane >> 4) * 8;
            bf16x8 v;
            if (n < O_N) {
                const float* p = ow + ((size_t)a * O_N + n) * H_N + k;
                f32x4 f0 = *(const f32x4*)p, f1 = *(const f32x4*)(p + 4);
                #pragma unroll
                for (int j = 0; j < 4; ++j) { v[j] = (__bf16)f0[j]; v[4 + j] = (__bf16)f1[j]; }
            } else {
                #pragma unroll
                for (int j = 0; j < 8; ++j) v[j] = (__bf16)0.f;
            }
            *(bf16x8*)(ws + OW_OFF + (size_t)a * 3072 + ks * 512 + lane * 8) = v;
        }
    }
}

// Operand-swapped MFMA: weights = A, activations = B.
// D: col(weight-col) = quad*4+reg, row(batch-row) = lane&15.
#define MFMA(a, b, c) __builtin_amdgcn_mfma_f32_16x16x32_bf16((a), (b), (c), 0, 0, 0)

// Round-4 lessons: barrier cut + zero-peel were NEUTRAL (srek 148->147.5); spill
// traffic (45->109 MB) is latency-hidden and NOT time-critical. (256,4) always
// spills catastrophically (rounds 2-3) -> stay (256,3).
// This round: (a) bias vectors as the ks0 MFMA C-operand (kills epilogue bias adds,
// ~290 VALU/wave; bit-identical since C layout reg<->col matches the bias slot);
// (b) s_setprio(1) around MFMA passes: resident blocks sit at diverse phases
// (occupancy 30%, 3 blocks/CU), the regime where priority arbitration pays.
__global__ __launch_bounds__(256, 3)
void srek_mfma(const float* __restrict__ x,
               const float* __restrict__ inw, const float* __restrict__ inb,
               const float* __restrict__ b1,  const float* __restrict__ b2,
               const float* __restrict__ b3,  const float* __restrict__ s1b,
               const float* __restrict__ s2b, const float* __restrict__ hnw,
               const float* __restrict__ hnb, const float* __restrict__ ob,
               const __bf16* __restrict__ ws, float* __restrict__ out) {
    __shared__ __bf16 bufA[24 * 512];  // x_norm (8x512 used) -> h2 (24 KB)
    __shared__ __bf16 bufB[24 * 512];  // h1 -> h3            (24 KB)

    const int bid  = blockIdx.x;
    const int slot = bid >> 3;
    const int tile = slot & 63;
    const int a    = ((bid & 7) << 3) | (slot >> 6);   // agent pinned to XCD
    const int row0 = tile * 64;

    const int tid  = threadIdx.x;
    const int lane = tid & 63;
    const int wv   = tid >> 6;     // col-quarter
    const int ln   = lane & 15;
    const int quad = lane >> 4;
    const int aH   = a * H_N;
    const int c0   = wv * 48;
    const int l8   = lane * 8;
    const int f3   = wv * 3;       // this wave's nt base (3 disjoint col-tiles)

    const __bf16* W1 = ws + W1_OFF + (size_t)a * 12288;
    const __bf16* S1 = ws + S1_OFF + (size_t)a * 12288;
    const __bf16* W2 = ws + W2_OFF + (size_t)a * 36864;
    const __bf16* S2 = ws + S2_OFF + (size_t)a * 36864;
    const __bf16* W3 = ws + W3_OFF + (size_t)a * 36864;
    const __bf16* OWp= ws + OW_OFF + (size_t)a * 3072;

    bf16x8 nxt[6];
    f32x4 accT[12], accS[12], h2f[12];
    f32x4 biT[3], biS[3];          // per-t bias C-init vectors (col = quad*4+rg)
    const f32x4 fzero = {0.f, 0.f, 0.f, 0.f};

    // prefetch L1 ks0 (this wave's 3 W + 3 S frags) + L1 biases
    #pragma unroll
    for (int t = 0; t < 3; ++t) {
        nxt[t]     = *(const bf16x8*)(W1 + ((f3 + t) * 2 + 0) * 512 + l8);
        nxt[3 + t] = *(const bf16x8*)(S1 + ((f3 + t) * 2 + 0) * 512 + l8);
        biT[t] = *(const f32x4*)(b1  + aH + c0 + t * 16 + quad * 4);
        biS[t] = *(const f32x4*)(s1b + aH + c0 + t * 16 + quad * 4);
    }

    // x_norm -> bufA frag-major [mt4][ks2][512] (hides prefetch latency)
    for (int e = tid; e < 8 * 512; e += 256) {
        int j   = e & 7;
        int lnn = (e >> 3) & 15;
        int qd  = (e >> 7) & 3;
        int kss = (e >> 9) & 1;
        int mtt = (e >> 10) & 3;
        int r = mtt * 16 + lnn;
        int k = kss * 32 + qd * 8 + j;
        float v = 0.f;
        if (k < D_N) v = x[(size_t)(row0 + r) * D_N + k] * inw[a * D_N + k] + inb[a * D_N + k];
        bufA[e] = (__bf16)v;
    }

    // first variants: C-operand = bias vector (replaces zero-init AND epilogue add)
    auto compute_dual_first = [&](const __bf16* As, int KS, int ks,
                                  const bf16x8* cw, const bf16x8* cs) {
        __builtin_amdgcn_s_setprio(1);
        #pragma unroll
        for (int mt = 0; mt < 4; ++mt) {
            bf16x8 av = *(const bf16x8*)(As + (mt * KS + ks) * 512 + l8);
            #pragma unroll
            for (int t = 0; t < 3; ++t) {
                accT[mt * 3 + t] = MFMA(cw[t], av, biT[t]);
                accS[mt * 3 + t] = MFMA(cs[t], av, biS[t]);
            }
        }
        __builtin_amdgcn_s_setprio(0);
    };
    auto compute_dual = [&](const __bf16* As, int KS, int ks,
                            const bf16x8* cw, const bf16x8* cs) {
        __builtin_amdgcn_s_setprio(1);
        #pragma unroll
        for (int mt = 0; mt < 4; ++mt) {
            bf16x8 av = *(const bf16x8*)(As + (mt * KS + ks) * 512 + l8);
            #pragma unroll
            for (int t = 0; t < 3; ++t) {
                accT[mt * 3 + t] = MFMA(cw[t], av, accT[mt * 3 + t]);
                accS[mt * 3 + t] = MFMA(cs[t], av, accS[mt * 3 + t]);
            }
        }
        __builtin_amdgcn_s_setprio(0);
    };
    auto compute_single_first = [&](const __bf16* As, int ks, const bf16x8* cw) {
        __builtin_amdgcn_s_setprio(1);
        #pragma unroll
        for (int mt = 0; mt < 4; ++mt) {
            bf16x8 av = *(const bf16x8*)(As + (mt * 6 + ks) * 512 + l8);
            #pragma unroll
            for (int t = 0; t < 3; ++t)
                accT[mt * 3 + t] = MFMA(cw[t], av, biT[t]);
        }
        __builtin_amdgcn_s_setprio(0);
    };
    auto compute_single = [&](const __bf16* As, int ks, const bf16x8* cw) {
        __builtin_amdgcn_s_setprio(1);
        #pragma unroll
        for (int mt = 0; mt < 4; ++mt) {
            bf16x8 av = *(const bf16x8*)(As + (mt * 6 + ks) * 512 + l8);
            #pragma unroll
            for (int t = 0; t < 3; ++t)
                accT[mt * 3 + t] = MFMA(cw[t], av, accT[mt * 3 + t]);
        }
        __builtin_amdgcn_s_setprio(0);
    };
    // store 12 f32x4 (C-layout) into dst frag-major as bf16
    auto store_fragmajor = [&](__bf16* dst, const f32x4* src) {
        #pragma unroll
        for (int t = 0; t < 3; ++t) {
            int ks2 = (3 * wv + t) >> 1;                       // (48wv+16t)>>5
            int qp  = (6 * wv + 2 * t + (quad >> 1)) & 3;      // chunk within frag
            int off = (qp * 16 + ln) * 8 + (quad & 1) * 4;     // 8B-aligned
            #pragma unroll
            for (int mt = 0; mt < 4; ++mt) {
                bf16x4 o;
                #pragma unroll
                for (int rg = 0; rg < 4; ++rg) o[rg] = (__bf16)src[mt * 3 + t][rg];
                *(bf16x4*)(dst + (mt * 6 + ks2) * 512 + off) = o;
            }
        }
    };

    __syncthreads();                                   // B1: x_norm (bufA) ready

    // ================= layer1 + skip1 (K=64, 2 chunks) =================
    {
        bf16x8 cw[3], cs[3];
        #pragma unroll
        for (int t = 0; t < 3; ++t) { cw[t] = nxt[t]; cs[t] = nxt[3 + t]; }
        #pragma unroll
        for (int t = 0; t < 3; ++t) {                  // prefetch L1 ks1
            nxt[t]     = *(const bf16x8*)(W1 + ((f3 + t) * 2 + 1) * 512 + l8);
            nxt[3 + t] = *(const bf16x8*)(S1 + ((f3 + t) * 2 + 1) * 512 + l8);
        }
        compute_dual_first(bufA, 2, 0, cw, cs);        // C-init = b1 / s1b
        #pragma unroll
        for (int t = 0; t < 3; ++t) { cw[t] = nxt[t]; cs[t] = nxt[3 + t]; }
        #pragma unroll
        for (int t = 0; t < 3; ++t) {                  // prefetch L2 ks0
            nxt[t]     = *(const bf16x8*)(W2 + ((f3 + t) * 6 + 0) * 512 + l8);
            nxt[3 + t] = *(const bf16x8*)(S2 + ((f3 + t) * 6 + 0) * 512 + l8);
        }
        compute_dual(bufA, 2, 1, cw, cs);
    }
    // epilogue L1: h1 = gelu(T) + S   (biases already inside acc) -> bufB
    #pragma unroll
    for (int t = 0; t < 3; ++t) {
        #pragma unroll
        for (int mt = 0; mt < 4; ++mt)
            #pragma unroll
            for (int rg = 0; rg < 4; ++rg)
                h2f[mt * 3 + t][rg] = gelu_f(accT[mt * 3 + t][rg]) + accS[mt * 3 + t][rg];
        biT[t] = *(const f32x4*)(b2  + aH + c0 + t * 16 + quad * 4);   // L2 biases
        biS[t] = *(const f32x4*)(s2b + aH + c0 + t * 16 + quad * 4);
    }
    store_fragmajor(bufB, h2f);
    __syncthreads();                                   // B2: h1 (bufB) ready

    // ================= layer2 + skip2 (K=192, 6 chunks) =================
    #pragma unroll
    for (int ks = 0; ks < 6; ++ks) {
        bf16x8 cw[3], cs[3];
        #pragma unroll
        for (int t = 0; t < 3; ++t) { cw[t] = nxt[t]; cs[t] = nxt[3 + t]; }
        if (ks < 5) {
            #pragma unroll
            for (int t = 0; t < 3; ++t) {
                nxt[t]     = *(const bf16x8*)(W2 + ((f3 + t) * 6 + ks + 1) * 512 + l8);
                nxt[3 + t] = *(const bf16x8*)(S2 + ((f3 + t) * 6 + ks + 1) * 512 + l8);
            }
        } else {
            #pragma unroll
            for (int t = 0; t < 3; ++t)                // prefetch L3 ks0
                nxt[t] = *(const bf16x8*)(W3 + ((f3 + t) * 6 + 0) * 512 + l8);
        }
        if (ks == 0) compute_dual_first(bufB, 6, ks, cw, cs);   // C-init = b2 / s2b
        else         compute_dual(bufB, 6, ks, cw, cs);
    }
    // h2 in fp32 registers (precision-critical residual); biases already inside
    #pragma unroll
    for (int t = 0; t < 3; ++t) {
        #pragma unroll
        for (int mt = 0; mt < 4; ++mt)
            #pragma unroll
            for (int rg = 0; rg < 4; ++rg)
                h2f[mt * 3 + t][rg] = gelu_f(accT[mt * 3 + t][rg]) + accS[mt * 3 + t][rg];
        biT[t] = *(const f32x4*)(b3 + aH + c0 + t * 16 + quad * 4);    // L3 bias
    }
    // h2 -> bufA (x_norm reads all finished before B2; no extra barrier needed)
    store_fragmajor(bufA, h2f);
    __syncthreads();                                   // B3: h2 (bufA) ready

    // ================= layer3 (K=192) =================
    bf16x8 ow6[6];
    #pragma unroll
    for (int ks = 0; ks < 6; ++ks) {
        bf16x8 cw[3];
        #pragma unroll
        for (int t = 0; t < 3; ++t) cw[t] = nxt[t];
        if (ks < 5) {
            #pragma unroll
            for (int t = 0; t < 3; ++t)
                nxt[t] = *(const bf16x8*)(W3 + ((f3 + t) * 6 + ks + 1) * 512 + l8);
        } else {
            #pragma unroll
            for (int kk = 0; kk < 6; ++kk)             // prefetch OW
                ow6[kk] = *(const bf16x8*)(OWp + kk * 512 + l8);
        }
        if (ks == 0) compute_single_first(bufA, ks, cw);        // C-init = b3
        else         compute_single(bufA, ks, cw);
    }
    // h3 = (acc + h2)*hnw + hnb   (b3 already inside acc)
    #pragma unroll
    for (int t = 0; t < 3; ++t) {
        int colb = c0 + t * 16 + quad * 4;
        f32x4 nwv = *(const f32x4*)(hnw + aH + colb);
        f32x4 nbv = *(const f32x4*)(hnb + aH + colb);
        #pragma unroll
        for (int mt = 0; mt < 4; ++mt)
            #pragma unroll
            for (int rg = 0; rg < 4; ++rg)
                h2f[mt * 3 + t][rg] = fmaf(accT[mt * 3 + t][rg] + h2f[mt * 3 + t][rg],
                                           nwv[rg], nbv[rg]);
    }
    // h3 -> bufB (h1 reads all finished before B3; no extra barrier needed)
    store_fragmajor(bufB, h2f);
    __syncthreads();                                   // B4: h3 (bufB) ready

    // ================= output (wave wv = row-mtile wv) =================
    {
        f32x4 acco = fzero;
        __builtin_amdgcn_s_setprio(1);
        #pragma unroll
        for (int ks = 0; ks < 6; ++ks) {
            bf16x8 av = *(const bf16x8*)(bufB + (wv * 6 + ks) * 512 + l8);
            acco = MFMA(ow6[ks], av, acco);
        }
        __builtin_amdgcn_s_setprio(0);
        if (quad == 0) {                               // o = rg (0..2), rows = wv*16+ln
            float* po = out + ((size_t)a * B_N + row0 + wv * 16 + ln) * O_N;
            po[0] = acco[0] + ob[a * O_N + 0];
            po[1] = acco[1] + ob[a * O_N + 1];
            po[2] = acco[2] + ob[a * O_N + 2];
        }
    }
}

extern "C" void kernel_launch(void* const* d_in, const int* in_sizes, int n_in,
                              void* d_out, int out_size, void* d_ws, size_t ws_size,
                              hipStream_t stream) {
    const float* x   = (const float*)d_in[0];
    const float* inw = (const float*)d_in[1];
    const float* inb = (const float*)d_in[2];
    const float* w1  = (const float*)d_in[3];
    const float* b1  = (const float*)d_in[4];
    const float* w2  = (const float*)d_in[5];
    const float* b2  = (const float*)d_in[6];
    const float* w3  = (const float*)d_in[7];
    const float* b3  = (const float*)d_in[8];
    const float* ow  = (const float*)d_in[9];
    const float* ob  = (const float*)d_in[10];
    const float* s1w = (const float*)d_in[11];
    const float* s1b = (const float*)d_in[12];
    const float* s2w = (const float*)d_in[13];
    const float* s2b = (const float*)d_in[14];
    const float* hnw = (const float*)d_in[15];
    const float* hnb = (const float*)d_in[16];

    __bf16* ws = (__bf16*)d_ws;   // 17.7 MB of d_ws

    prep_kernel<<<dim3(1292), dim3(256), 0, stream>>>(w1, s1w, w2, s2w, w3, ow, ws);

    srek_mfma<<<dim3(A_N * (B_N / 64)), dim3(256), 0, stream>>>(
        x, inw, inb, b1, b2, b3, s1b, s2b, hnw, hnb, ob, ws, (float*)d_out);
}

// Round 6
// 240.563 us; speedup vs baseline: 1.3186x; 1.3186x over previous
//
#include <hip/hip_runtime.h>
#include <math.h>

#define A_N 64
#define B_N 4096
#define D_N 50
#define H_N 192
#define O_N 3

typedef __attribute__((ext_vector_type(8))) __bf16 bf16x8;
typedef __attribute__((ext_vector_type(4))) __bf16 bf16x4;
typedef __attribute__((ext_vector_type(4))) float f32x4;

// ws layout (bf16 elems), frag-packed: frag elem (lane,j) = W[nt*16+(lane&15)][ks*32+(lane>>4)*8+j]
#define W1_OFF   0          // [A][12 nt][2 ks][512]   K=64 (padded from 50)
#define S1_OFF   786432
#define W2_OFF   1572864    // [A][12 nt][6 ks][512]   K=192
#define S2_OFF   3932160
#define W3_OFF   6291456
#define OW_OFF   8650752    // [A][6 ks][512]          N=16 (padded from 3), K=192
#define WS_ELEMS 8847360    // *2 B = 17.7 MB of d_ws

#if __has_builtin(__builtin_amdgcn_rcpf)
#define FRCP(x) __builtin_amdgcn_rcpf(x)
#else
#define FRCP(x) (1.0f / (x))
#endif
#if __has_builtin(__builtin_amdgcn_exp2f)
#define FEXP2(x) __builtin_amdgcn_exp2f(x)
#else
#define FEXP2(x) exp2f(x)
#endif

// A&S 7.1.26 erf (|eps|<=1.5e-7) + native rcp/exp2
__device__ __forceinline__ float gelu_f(float xx) {
    float t  = 0.70710678118654752440f * xx;
    float at = fabsf(t);
    float k  = FRCP(fmaf(0.3275911f, at, 1.0f));
    float p  = fmaf(k, 1.061405429f, -1.453152027f);
    p = fmaf(k, p, 1.421413741f);
    p = fmaf(k, p, -0.284496736f);
    p = fmaf(k, p, 0.254829592f);
    p = p * k;
    float e  = FEXP2(t * t * -1.44269504088896340736f);
    float er = fmaf(-p, e, 1.0f);
    er = (t < 0.f) ? -er : er;
    return 0.5f * xx * (1.0f + er);
}

// Prep v3 (HW-validated). Round-1 lesson: prep is ~8 us of BW-bound work; the ~78 us
// total-vs-srek gap is FIXED harness overhead (noisy +-15us). Do NOT delete prep.
__global__ __launch_bounds__(256)
void prep_kernel(const float* __restrict__ w1, const float* __restrict__ s1,
                 const float* __restrict__ w2, const float* __restrict__ s2,
                 const float* __restrict__ w3, const float* __restrict__ ow,
                 __bf16* __restrict__ ws) {
    __shared__ __bf16 T[192 * 72];   // sec A uses [32][200] = 6400 of it
    const int b   = blockIdx.x;
    const int tid = threadIdx.x;

    if (b < 1152) {
        int m  = b / 384;                 // 0=w2 1=s2 2=w3
        int r  = b % 384;
        int a  = r / 6;
        int rc = r % 6;                   // 32-row chunk
        const float* src = ((m == 0) ? w2 : (m == 1) ? s2 : w3) + (size_t)a * 36864;
        __bf16* dst = ws + ((m == 0) ? W2_OFF : (m == 1) ? S2_OFF : W3_OFF) + (size_t)a * 36864;
        #pragma unroll
        for (int i = 0; i < 6; ++i) {                 // 1536 float4 = 32 rows x 192 cols
            int f4 = i * 256 + tid;
            int row = f4 / 48, kc = (f4 % 48) * 4;
            f32x4 v = *(const f32x4*)(src + (size_t)(rc * 32 + row) * 192 + kc);
            bf16x4 o;
            #pragma unroll
            for (int j = 0; j < 4; ++j) o[j] = (__bf16)v[j];
            *(bf16x4*)(T + row * 200 + kc) = o;       // pitch 200: 2-way max
        }
        __syncthreads();
        #pragma unroll
        for (int i = 0; i < 3; ++i) {                 // 768 frag-rows (2 nt x 6 ks x 64)
            int fr = i * 256 + tid;
            int f = fr >> 6, lane = fr & 63;
            int ntl = f / 6, ks = f % 6;
            int n = ntl * 16 + (lane & 15), k = ks * 32 + (lane >> 4) * 8;
            bf16x8 v = *(const bf16x8*)(T + n * 200 + k);
            *(bf16x8*)(dst + ((size_t)(rc * 2 + ntl) * 6 + ks) * 512 + lane * 8) = v;
        }
    } else if (b < 1280) {
        int r = b - 1152; int m = r >> 6; int a = r & 63;
        const float* src = (m ? s1 : w1) + (size_t)a * 9600;
        __bf16* dst = ws + (m ? S1_OFF : W1_OFF) + (size_t)a * 12288;
        for (int e = tid; e < 192 * 72; e += 256) T[e] = (__bf16)0.f;
        __syncthreads();
        for (int e = tid; e < 9600; e += 256) {
            int row = e / 50, k = e - row * 50;
            T[row * 72 + k] = (__bf16)src[e];
        }
        __syncthreads();
        #pragma unroll
        for (int i = 0; i < 6; ++i) {                 // 1536 frag-rows (12 nt x 2 ks x 64)
            int fr = i * 256 + tid;
            int f = fr >> 6, lane = fr & 63;
            int nt = f >> 1, ks = f & 1;
            int n = nt * 16 + (lane & 15), k = ks * 32 + (lane >> 4) * 8;
            bf16x8 v = *(const bf16x8*)(T + n * 72 + k);
            *(bf16x8*)(dst + (size_t)(nt * 2 + ks) * 512 + lane * 8) = v;
        }
    } else {
        int r = b - 1280;
        #pragma unroll
        for (int i = 0; i < 8; ++i) {                 // 24576 frag-rows total
            int fr = (r * 8 + i) * 256 + tid;
            int a = fr / 384, rem = fr - a * 384;
            int ks = rem >> 6, lane = rem & 63;
            int n = lane & 15, k = ks * 32 + (lane >> 4) * 8;
            bf16x8 v;
            if (n < O_N) {
                const float* p = ow + ((size_t)a * O_N + n) * H_N + k;
                f32x4 f0 = *(const f32x4*)p, f1 = *(const f32x4*)(p + 4);
                #pragma unroll
                for (int j = 0; j < 4; ++j) { v[j] = (__bf16)f0[j]; v[4 + j] = (__bf16)f1[j]; }
            } else {
                #pragma unroll
                for (int j = 0; j < 8; ++j) v[j] = (__bf16)0.f;
            }
            *(bf16x8*)(ws + OW_OFF + (size_t)a * 3072 + ks * 512 + lane * 8) = v;
        }
    }
}

// Operand-swapped MFMA: weights = A, activations = B.
// D: col(weight-col) = quad*4+reg, row(batch-row) = lane&15.
#define MFMA(a, b, c) __builtin_amdgcn_mfma_f32_16x16x32_bf16((a), (b), (c), 0, 0, 0)

// ROUND 6: HALVED ROW-TILE (32 rows/block, 8192 blocks) + sequential T->S passes.
// Rationale: rounds 0-5 pinned the bottleneck on per-thread live state (48-elem
// output tile -> accT48+accS48+h2f48 regs -> 3 blocks/CU, 36% no-issue). Halving
// the tile gives 24-elem/thread: accT 24 + h2f 24 + nxt 12 + transients ~= 95-105
// regs -> genuinely fits the (256,4) cap of 128 (rounds 2/3 spilled because the
// FULL tile + sequential still needed ~140). Sequential-S re-reads act frags from
// LDS (cheap); numerics ordering identical to round-3 (which PASSED, absmax
// 1.525879e-05). Known risk: 2x per-wave weight L2 traffic (~56% per-XCD L2 BW).
// Round-5 lessons kept: no bias-C-init, no setprio.
__global__ __launch_bounds__(256, 4)
void srek_mfma(const float* __restrict__ x,
               const float* __restrict__ inw, const float* __restrict__ inb,
               const float* __restrict__ b1,  const float* __restrict__ b2,
               const float* __restrict__ b3,  const float* __restrict__ s1b,
               const float* __restrict__ s2b, const float* __restrict__ hnw,
               const float* __restrict__ hnb, const float* __restrict__ ob,
               const __bf16* __restrict__ ws, float* __restrict__ out) {
    __shared__ __bf16 bufA[12 * 512];  // x_norm (4x512 used) -> h2 (12 KB)
    __shared__ __bf16 bufB[12 * 512];  // h1 -> h3            (12 KB)

    const int bid  = blockIdx.x;
    const int slot = bid >> 3;
    const int tile = slot & 127;                       // 128 row-tiles of 32
    const int a    = ((bid & 7) << 3) | (slot >> 7);   // agent pinned to XCD
    const int row0 = tile * 32;

    const int tid  = threadIdx.x;
    const int lane = tid & 63;
    const int wv   = tid >> 6;     // col-quarter
    const int ln   = lane & 15;
    const int quad = lane >> 4;
    const int aH   = a * H_N;
    const int c0   = wv * 48;
    const int l8   = lane * 8;
    const int f3   = wv * 3;       // this wave's nt base (3 disjoint col-tiles)

    const __bf16* W1 = ws + W1_OFF + (size_t)a * 12288;
    const __bf16* S1 = ws + S1_OFF + (size_t)a * 12288;
    const __bf16* W2 = ws + W2_OFF + (size_t)a * 36864;
    const __bf16* S2 = ws + S2_OFF + (size_t)a * 36864;
    const __bf16* W3 = ws + W3_OFF + (size_t)a * 36864;
    const __bf16* OWp= ws + OW_OFF + (size_t)a * 3072;

    bf16x8 nxt[3];                 // single weight-trio prefetch pipeline
    f32x4 accT[6], h2f[6];         // 2 mt x 3 t
    const f32x4 fzero = {0.f, 0.f, 0.f, 0.f};

    // prefetch W1 ks0 (this wave's 3 frags)
    #pragma unroll
    for (int t = 0; t < 3; ++t)
        nxt[t] = *(const bf16x8*)(W1 + ((f3 + t) * 2 + 0) * 512 + l8);

    // x_norm -> bufA frag-major [mt2][ks2][512] (hides prefetch latency)
    for (int e = tid; e < 4 * 512; e += 256) {
        int j   = e & 7;
        int lnn = (e >> 3) & 15;
        int qd  = (e >> 7) & 3;
        int kss = (e >> 9) & 1;
        int mtt = (e >> 10) & 1;
        int r = mtt * 16 + lnn;
        int k = kss * 32 + qd * 8 + j;
        float v = 0.f;
        if (k < D_N) v = x[(size_t)(row0 + r) * D_N + k] * inw[a * D_N + k] + inb[a * D_N + k];
        bufA[e] = (__bf16)v;
    }

    // first=true: C-operand = fzero (no bulk acc zeroing; bit-identical)
    auto compute_first = [&](const __bf16* As, int KS, int ks, const bf16x8* cw) {
        #pragma unroll
        for (int mt = 0; mt < 2; ++mt) {
            bf16x8 av = *(const bf16x8*)(As + (mt * KS + ks) * 512 + l8);
            #pragma unroll
            for (int t = 0; t < 3; ++t)
                accT[mt * 3 + t] = MFMA(cw[t], av, fzero);
        }
    };
    auto compute_pass = [&](const __bf16* As, int KS, int ks, const bf16x8* cw) {
        #pragma unroll
        for (int mt = 0; mt < 2; ++mt) {
            bf16x8 av = *(const bf16x8*)(As + (mt * KS + ks) * 512 + l8);
            #pragma unroll
            for (int t = 0; t < 3; ++t)
                accT[mt * 3 + t] = MFMA(cw[t], av, accT[mt * 3 + t]);
        }
    };
    // h2f = gelu(acc + bias)
    auto ep_gelu = [&](const float* bias) {
        #pragma unroll
        for (int t = 0; t < 3; ++t) {
            f32x4 bb = *(const f32x4*)(bias + aH + c0 + t * 16 + quad * 4);
            #pragma unroll
            for (int mt = 0; mt < 2; ++mt)
                #pragma unroll
                for (int rg = 0; rg < 4; ++rg)
                    h2f[mt * 3 + t][rg] = gelu_f(accT[mt * 3 + t][rg] + bb[rg]);
        }
    };
    // h2f = (h2f + acc) + sbias   (round-3-verified ordering, bit-identical)
    auto ep_addskip = [&](const float* sbias) {
        #pragma unroll
        for (int t = 0; t < 3; ++t) {
            f32x4 sb = *(const f32x4*)(sbias + aH + c0 + t * 16 + quad * 4);
            #pragma unroll
            for (int mt = 0; mt < 2; ++mt)
                #pragma unroll
                for (int rg = 0; rg < 4; ++rg)
                    h2f[mt * 3 + t][rg] = (h2f[mt * 3 + t][rg] + accT[mt * 3 + t][rg]) + sb[rg];
        }
    };
    // store 6 f32x4 (C-layout) into dst frag-major as bf16
    auto store_fragmajor = [&](__bf16* dst, const f32x4* src) {
        #pragma unroll
        for (int t = 0; t < 3; ++t) {
            int ks2 = (3 * wv + t) >> 1;                       // (48wv+16t)>>5
            int qp  = (6 * wv + 2 * t + (quad >> 1)) & 3;      // chunk within frag
            int off = (qp * 16 + ln) * 8 + (quad & 1) * 4;     // 8B-aligned
            #pragma unroll
            for (int mt = 0; mt < 2; ++mt) {
                bf16x4 o;
                #pragma unroll
                for (int rg = 0; rg < 4; ++rg) o[rg] = (__bf16)src[mt * 3 + t][rg];
                *(bf16x4*)(dst + (mt * 6 + ks2) * 512 + off) = o;
            }
        }
    };

    __syncthreads();                                   // B1: x_norm (bufA) ready

    // ================= layer1 + skip1 (K=64; T pass then S pass) =================
    {
        bf16x8 cw[3];
        #pragma unroll
        for (int t = 0; t < 3; ++t) cw[t] = nxt[t];
        #pragma unroll
        for (int t = 0; t < 3; ++t)                    // prefetch W1 ks1
            nxt[t] = *(const bf16x8*)(W1 + ((f3 + t) * 2 + 1) * 512 + l8);
        compute_first(bufA, 2, 0, cw);
        #pragma unroll
        for (int t = 0; t < 3; ++t) cw[t] = nxt[t];
        #pragma unroll
        for (int t = 0; t < 3; ++t)                    // prefetch S1 ks0
            nxt[t] = *(const bf16x8*)(S1 + ((f3 + t) * 2 + 0) * 512 + l8);
        compute_pass(bufA, 2, 1, cw);
    }
    ep_gelu(b1);                                       // covers S1 prefetch latency
    {
        bf16x8 cw[3];
        #pragma unroll
        for (int t = 0; t < 3; ++t) cw[t] = nxt[t];
        #pragma unroll
        for (int t = 0; t < 3; ++t)                    // prefetch S1 ks1
            nxt[t] = *(const bf16x8*)(S1 + ((f3 + t) * 2 + 1) * 512 + l8);
        compute_first(bufA, 2, 0, cw);
        #pragma unroll
        for (int t = 0; t < 3; ++t) cw[t] = nxt[t];
        #pragma unroll
        for (int t = 0; t < 3; ++t)                    // prefetch W2 ks0
            nxt[t] = *(const bf16x8*)(W2 + ((f3 + t) * 6 + 0) * 512 + l8);
        compute_pass(bufA, 2, 1, cw);
    }
    ep_addskip(s1b);                                   // h1 done (fp32 in h2f)
    store_fragmajor(bufB, h2f);
    __syncthreads();                                   // B2: h1 (bufB) ready

    // ================= layer2 + skip2 (K=192; T pass then S pass) =================
    #pragma unroll
    for (int ks = 0; ks < 6; ++ks) {
        bf16x8 cw[3];
        #pragma unroll
        for (int t = 0; t < 3; ++t) cw[t] = nxt[t];
        #pragma unroll
        for (int t = 0; t < 3; ++t)
            nxt[t] = (ks < 5)
                ? *(const bf16x8*)(W2 + ((f3 + t) * 6 + ks + 1) * 512 + l8)
                : *(const bf16x8*)(S2 + ((f3 + t) * 6 + 0) * 512 + l8);
        if (ks == 0) compute_first(bufB, 6, ks, cw);
        else         compute_pass(bufB, 6, ks, cw);
    }
    ep_gelu(b2);
    #pragma unroll
    for (int ks = 0; ks < 6; ++ks) {
        bf16x8 cw[3];
        #pragma unroll
        for (int t = 0; t < 3; ++t) cw[t] = nxt[t];
        #pragma unroll
        for (int t = 0; t < 3; ++t)
            nxt[t] = (ks < 5)
                ? *(const bf16x8*)(S2 + ((f3 + t) * 6 + ks + 1) * 512 + l8)
                : *(const bf16x8*)(W3 + ((f3 + t) * 6 + 0) * 512 + l8);
        if (ks == 0) compute_first(bufB, 6, ks, cw);
        else         compute_pass(bufB, 6, ks, cw);
    }
    ep_addskip(s2b);                                   // h2 done (fp32 in h2f, kept for residual)
    // h2 -> bufA (x_norm reads all finished before B2; no extra barrier needed)
    store_fragmajor(bufA, h2f);
    __syncthreads();                                   // B3: h2 (bufA) ready

    // ================= layer3 (K=192) =================
    #pragma unroll
    for (int ks = 0; ks < 6; ++ks) {
        bf16x8 cw[3];
        #pragma unroll
        for (int t = 0; t < 3; ++t) cw[t] = nxt[t];
        if (ks < 5) {
            #pragma unroll
            for (int t = 0; t < 3; ++t)
                nxt[t] = *(const bf16x8*)(W3 + ((f3 + t) * 6 + ks + 1) * 512 + l8);
        }
        if (ks == 0) compute_first(bufA, 6, ks, cw);
        else         compute_pass(bufA, 6, ks, cw);
    }
    // h3 = (acc + b3 + h2)*hnw + hnb
    #pragma unroll
    for (int t = 0; t < 3; ++t) {
        int colb = c0 + t * 16 + quad * 4;
        f32x4 b3v = *(const f32x4*)(b3  + aH + colb);
        f32x4 nwv = *(const f32x4*)(hnw + aH + colb);
        f32x4 nbv = *(const f32x4*)(hnb + aH + colb);
        #pragma unroll
        for (int mt = 0; mt < 2; ++mt)
            #pragma unroll
            for (int rg = 0; rg < 4; ++rg)
                h2f[mt * 3 + t][rg] = fmaf(accT[mt * 3 + t][rg] + b3v[rg] + h2f[mt * 3 + t][rg],
                                           nwv[rg], nbv[rg]);
    }
    // h3 -> bufB (h1 reads all finished before B3; no extra barrier needed)
    store_fragmajor(bufB, h2f);
    __syncthreads();                                   // B4: h3 (bufB) ready

    // ================= output (waves 0,1 = row-mtiles 0,1) =================
    if (wv < 2) {
        bf16x8 ow6[6];
        #pragma unroll
        for (int kk = 0; kk < 6; ++kk)
            ow6[kk] = *(const bf16x8*)(OWp + kk * 512 + l8);
        f32x4 acco = fzero;
        #pragma unroll
        for (int ks = 0; ks < 6; ++ks) {
            bf16x8 av = *(const bf16x8*)(bufB + (wv * 6 + ks) * 512 + l8);
            acco = MFMA(ow6[ks], av, acco);
        }
        if (quad == 0) {                               // o = rg (0..2), rows = wv*16+ln
            float* po = out + ((size_t)a * B_N + row0 + wv * 16 + ln) * O_N;
            po[0] = acco[0] + ob[a * O_N + 0];
            po[1] = acco[1] + ob[a * O_N + 1];
            po[2] = acco[2] + ob[a * O_N + 2];
        }
    }
}

extern "C" void kernel_launch(void* const* d_in, const int* in_sizes, int n_in,
                              void* d_out, int out_size, void* d_ws, size_t ws_size,
                              hipStream_t stream) {
    const float* x   = (const float*)d_in[0];
    const float* inw = (const float*)d_in[1];
    const float* inb = (const float*)d_in[2];
    const float* w1  = (const float*)d_in[3];
    const float* b1  = (const float*)d_in[4];
    const float* w2  = (const float*)d_in[5];
    const float* b2  = (const float*)d_in[6];
    const float* w3  = (const float*)d_in[7];
    const float* b3  = (const float*)d_in[8];
    const float* ow  = (const float*)d_in[9];
    const float* ob  = (const float*)d_in[10];
    const float* s1w = (const float*)d_in[11];
    const float* s1b = (const float*)d_in[12];
    const float* s2w = (const float*)d_in[13];
    const float* s2b = (const float*)d_in[14];
    const float* hnw = (const float*)d_in[15];
    const float* hnb = (const float*)d_in[16];

    __bf16* ws = (__bf16*)d_ws;   // 17.7 MB of d_ws

    prep_kernel<<<dim3(1292), dim3(256), 0, stream>>>(w1, s1w, w2, s2w, w3, ow, ws);

    srek_mfma<<<dim3(A_N * (B_N / 32)), dim3(256), 0, stream>>>(
        x, inw, inb, b1, b2, b3, s1b, s2b, hnw, hnb, ob, ws, (float*)d_out);
}

// Round 7
// 227.864 us; speedup vs baseline: 1.3921x; 1.0557x over previous
//
#include <hip/hip_runtime.h>
#include <math.h>

#define A_N 64
#define B_N 4096
#define D_N 50
#define H_N 192
#define O_N 3

typedef __attribute__((ext_vector_type(8))) __bf16 bf16x8;
typedef __attribute__((ext_vector_type(4))) __bf16 bf16x4;
typedef __attribute__((ext_vector_type(4))) float f32x4;
typedef __attribute__((ext_vector_type(2))) float f32x2;

// ws layout (bf16 elems), frag-packed: frag elem (lane,j) = W[nt*16+(lane&15)][ks*32+(lane>>4)*8+j]
#define W1_OFF   0          // [A][12 nt][2 ks][512]   K=64 (padded from 50)
#define S1_OFF   786432
#define W2_OFF   1572864    // [A][12 nt][6 ks][512]   K=192
#define S2_OFF   3932160
#define W3_OFF   6291456
#define OW_OFF   8650752    // [A][6 ks][512]          N=16 (padded from 3), K=192
#define WS_ELEMS 8847360    // *2 B = 17.7 MB of d_ws

#if __has_builtin(__builtin_amdgcn_rcpf)
#define FRCP(x) __builtin_amdgcn_rcpf(x)
#else
#define FRCP(x) (1.0f / (x))
#endif
#if __has_builtin(__builtin_amdgcn_exp2f)
#define FEXP2(x) __builtin_amdgcn_exp2f(x)
#else
#define FEXP2(x) exp2f(x)
#endif

// ---- packed-f32 helpers (CDNA v_pk_fma_f32 / v_pk_mul_f32 / v_pk_add_f32) ----
static __device__ __forceinline__ f32x2 f2(float v)            { f32x2 r; r[0] = v;    r[1] = v;    return r; }
static __device__ __forceinline__ f32x2 lo2(f32x4 v)           { f32x2 r; r[0] = v[0]; r[1] = v[1]; return r; }
static __device__ __forceinline__ f32x2 hi2(f32x4 v)           { f32x2 r; r[0] = v[2]; r[1] = v[3]; return r; }
static __device__ __forceinline__ f32x4 cmb(f32x2 a, f32x2 b)  { f32x4 r; r[0] = a[0]; r[1] = a[1]; r[2] = b[0]; r[3] = b[1]; return r; }
static __device__ __forceinline__ f32x2 fma2(f32x2 a, f32x2 b, f32x2 c) {
#if __has_builtin(__builtin_elementwise_fma)
    return __builtin_elementwise_fma(a, b, c);
#else
    f32x2 r; r[0] = fmaf(a[0], b[0], c[0]); r[1] = fmaf(a[1], b[1], c[1]); return r;
#endif
}
static __device__ __forceinline__ f32x2 abs2(f32x2 v) {
#if __has_builtin(__builtin_elementwise_abs)
    return __builtin_elementwise_abs(v);
#else
    f32x2 r; r[0] = fabsf(v[0]); r[1] = fabsf(v[1]); return r;
#endif
}

// A&S 7.1.26 erf, packed 2-wide. Sign-free: x*erf(x/sqrt2) = |x|*erf(|x|/sqrt2)
// (erf odd) -> gelu = 0.7071*(t + |t|*er), no cmp/cndmask. fma chain values
// identical to the scalar version; only the final combine reorders (~1ulp f32).
__device__ __forceinline__ f32x2 gelu2(f32x2 xx) {
    const f32x2 chs = f2(0.70710678118654752440f);
    f32x2 t  = xx * chs;
    f32x2 at = abs2(t);
    f32x2 d  = fma2(at, f2(0.3275911f), f2(1.0f));
    f32x2 k; k[0] = FRCP(d[0]); k[1] = FRCP(d[1]);
    f32x2 p  = fma2(k, f2(1.061405429f), f2(-1.453152027f));
    p = fma2(k, p, f2(1.421413741f));
    p = fma2(k, p, f2(-0.284496736f));
    p = fma2(k, p, f2(0.254829592f));
    p = p * k;
    f32x2 t2 = t * t;
    f32x2 a2 = t2 * f2(-1.44269504088896340736f);
    f32x2 e; e[0] = FEXP2(a2[0]); e[1] = FEXP2(a2[1]);
    f32x2 er = fma2(-p, e, f2(1.0f));
    f32x2 r  = fma2(at, er, t);
    return r * chs;
}

// Prep v3 (HW-validated). Round-1 lesson: prep is ~8 us of BW-bound work; the ~78 us
// total-vs-srek gap is FIXED harness overhead (noisy +-15us). Do NOT delete prep.
__global__ __launch_bounds__(256)
void prep_kernel(const float* __restrict__ w1, const float* __restrict__ s1,
                 const float* __restrict__ w2, const float* __restrict__ s2,
                 const float* __restrict__ w3, const float* __restrict__ ow,
                 __bf16* __restrict__ ws) {
    __shared__ __bf16 T[192 * 72];   // sec A uses [32][200] = 6400 of it
    const int b   = blockIdx.x;
    const int tid = threadIdx.x;

    if (b < 1152) {
        int m  = b / 384;                 // 0=w2 1=s2 2=w3
        int r  = b % 384;
        int a  = r / 6;
        int rc = r % 6;                   // 32-row chunk
        const float* src = ((m == 0) ? w2 : (m == 1) ? s2 : w3) + (size_t)a * 36864;
        __bf16* dst = ws + ((m == 0) ? W2_OFF : (m == 1) ? S2_OFF : W3_OFF) + (size_t)a * 36864;
        #pragma unroll
        for (int i = 0; i < 6; ++i) {                 // 1536 float4 = 32 rows x 192 cols
            int f4 = i * 256 + tid;
            int row = f4 / 48, kc = (f4 % 48) * 4;
            f32x4 v = *(const f32x4*)(src + (size_t)(rc * 32 + row) * 192 + kc);
            bf16x4 o;
            #pragma unroll
            for (int j = 0; j < 4; ++j) o[j] = (__bf16)v[j];
            *(bf16x4*)(T + row * 200 + kc) = o;       // pitch 200: 2-way max
        }
        __syncthreads();
        #pragma unroll
        for (int i = 0; i < 3; ++i) {                 // 768 frag-rows (2 nt x 6 ks x 64)
            int fr = i * 256 + tid;
            int f = fr >> 6, lane = fr & 63;
            int ntl = f / 6, ks = f % 6;
            int n = ntl * 16 + (lane & 15), k = ks * 32 + (lane >> 4) * 8;
            bf16x8 v = *(const bf16x8*)(T + n * 200 + k);
            *(bf16x8*)(dst + ((size_t)(rc * 2 + ntl) * 6 + ks) * 512 + lane * 8) = v;
        }
    } else if (b < 1280) {
        int r = b - 1152; int m = r >> 6; int a = r & 63;
        const float* src = (m ? s1 : w1) + (size_t)a * 9600;
        __bf16* dst = ws + (m ? S1_OFF : W1_OFF) + (size_t)a * 12288;
        for (int e = tid; e < 192 * 72; e += 256) T[e] = (__bf16)0.f;
        __syncthreads();
        for (int e = tid; e < 9600; e += 256) {
            int row = e / 50, k = e - row * 50;
            T[row * 72 + k] = (__bf16)src[e];
        }
        __syncthreads();
        #pragma unroll
        for (int i = 0; i < 6; ++i) {                 // 1536 frag-rows (12 nt x 2 ks x 64)
            int fr = i * 256 + tid;
            int f = fr >> 6, lane = fr & 63;
            int nt = f >> 1, ks = f & 1;
            int n = nt * 16 + (lane & 15), k = ks * 32 + (lane >> 4) * 8;
            bf16x8 v = *(const bf16x8*)(T + n * 72 + k);
            *(bf16x8*)(dst + (size_t)(nt * 2 + ks) * 512 + lane * 8) = v;
        }
    } else {
        int r = b - 1280;
        #pragma unroll
        for (int i = 0; i < 8; ++i) {                 // 24576 frag-rows total
            int fr = (r * 8 + i) * 256 + tid;
            int a = fr / 384, rem = fr - a * 384;
            int ks = rem >> 6, lane = rem & 63;
            int n = lane & 15, k = ks * 32 + (lane >> 4) * 8;
            bf16x8 v;
            if (n < O_N) {
                const float* p = ow + ((size_t)a * O_N + n) * H_N + k;
                f32x4 f0 = *(const f32x4*)p, f1 = *(const f32x4*)(p + 4);
                #pragma unroll
                for (int j = 0; j < 4; ++j) { v[j] = (__bf16)f0[j]; v[4 + j] = (__bf16)f1[j]; }
            } else {
                #pragma unroll
                for (int j = 0; j < 8; ++j) v[j] = (__bf16)0.f;
            }
            *(bf16x8*)(ws + OW_OFF + (size_t)a * 3072 + ks * 512 + lane * 8) = v;
        }
    }
}

// Operand-swapped MFMA: weights = A, activations = B.
// D: col(weight-col) = quad*4+reg, row(batch-row) = lane&15.
#define MFMA(a, b, c) __builtin_amdgcn_mfma_f32_16x16x32_bf16((a), (b), (c), 0, 0, 0)

// ROUND 7: round-4 base (147.5 us proven; ping-pong LDS, dual accT/accS, fzero-peel,
// (256,3)) + PACKED-F32 VALU CUT. Cross-round invariant (R0/R4/R6): MFMA-busy ~31us
// and VALU-busy ~64-68us are constant; wall = ~2.3x VALU-busy. Occupancy (R6: 42%)
// did NOT help -> kernel is VALU-work-dominated; gelu (100.7M evals x ~16 ops) is
// the hog. This round halves the gelu/epilogue VALU op count via f32x2 ext-vector
// math (v_pk_fma_f32/v_pk_mul_f32/v_pk_add_f32) + sign-free erf (no cmp/cndmask).
// Lessons kept: no (256,4) [always spills], no bias-C-init [R5: +24 live regs ->
// spill in loops], no setprio, prep stays.
__global__ __launch_bounds__(256, 3)
void srek_mfma(const float* __restrict__ x,
               const float* __restrict__ inw, const float* __restrict__ inb,
               const float* __restrict__ b1,  const float* __restrict__ b2,
               const float* __restrict__ b3,  const float* __restrict__ s1b,
               const float* __restrict__ s2b, const float* __restrict__ hnw,
               const float* __restrict__ hnb, const float* __restrict__ ob,
               const __bf16* __restrict__ ws, float* __restrict__ out) {
    __shared__ __bf16 bufA[24 * 512];  // x_norm (8x512 used) -> h2 (24 KB)
    __shared__ __bf16 bufB[24 * 512];  // h1 -> h3            (24 KB)

    const int bid  = blockIdx.x;
    const int slot = bid >> 3;
    const int tile = slot & 63;
    const int a    = ((bid & 7) << 3) | (slot >> 6);   // agent pinned to XCD
    const int row0 = tile * 64;

    const int tid  = threadIdx.x;
    const int lane = tid & 63;
    const int wv   = tid >> 6;     // col-quarter
    const int ln   = lane & 15;
    const int quad = lane >> 4;
    const int aH   = a * H_N;
    const int c0   = wv * 48;
    const int l8   = lane * 8;
    const int f3   = wv * 3;       // this wave's nt base (3 disjoint col-tiles)

    const __bf16* W1 = ws + W1_OFF + (size_t)a * 12288;
    const __bf16* S1 = ws + S1_OFF + (size_t)a * 12288;
    const __bf16* W2 = ws + W2_OFF + (size_t)a * 36864;
    const __bf16* S2 = ws + S2_OFF + (size_t)a * 36864;
    const __bf16* W3 = ws + W3_OFF + (size_t)a * 36864;
    const __bf16* OWp= ws + OW_OFF + (size_t)a * 3072;

    bf16x8 nxt[6];
    f32x4 accT[12], accS[12], h2f[12];
    const f32x4 fzero = {0.f, 0.f, 0.f, 0.f};

    // prefetch L1 ks0 (this wave's 3 W + 3 S frags)
    #pragma unroll
    for (int t = 0; t < 3; ++t) {
        nxt[t]     = *(const bf16x8*)(W1 + ((f3 + t) * 2 + 0) * 512 + l8);
        nxt[3 + t] = *(const bf16x8*)(S1 + ((f3 + t) * 2 + 0) * 512 + l8);
    }

    // x_norm -> bufA frag-major [mt4][ks2][512] (hides prefetch latency)
    for (int e = tid; e < 8 * 512; e += 256) {
        int j   = e & 7;
        int lnn = (e >> 3) & 15;
        int qd  = (e >> 7) & 3;
        int kss = (e >> 9) & 1;
        int mtt = (e >> 10) & 3;
        int r = mtt * 16 + lnn;
        int k = kss * 32 + qd * 8 + j;
        float v = 0.f;
        if (k < D_N) v = x[(size_t)(row0 + r) * D_N + k] * inw[a * D_N + k] + inb[a * D_N + k];
        bufA[e] = (__bf16)v;
    }

    // first=true: C-operand is fzero (replaces bulk acc zeroing, bit-identical)
    auto compute_dual_first = [&](const __bf16* As, int KS, int ks,
                                  const bf16x8* cw, const bf16x8* cs) {
        #pragma unroll
        for (int mt = 0; mt < 4; ++mt) {
            bf16x8 av = *(const bf16x8*)(As + (mt * KS + ks) * 512 + l8);
            #pragma unroll
            for (int t = 0; t < 3; ++t) {
                accT[mt * 3 + t] = MFMA(cw[t], av, fzero);
                accS[mt * 3 + t] = MFMA(cs[t], av, fzero);
            }
        }
    };
    auto compute_dual = [&](const __bf16* As, int KS, int ks,
                            const bf16x8* cw, const bf16x8* cs) {
        #pragma unroll
        for (int mt = 0; mt < 4; ++mt) {
            bf16x8 av = *(const bf16x8*)(As + (mt * KS + ks) * 512 + l8);
            #pragma unroll
            for (int t = 0; t < 3; ++t) {
                accT[mt * 3 + t] = MFMA(cw[t], av, accT[mt * 3 + t]);
                accS[mt * 3 + t] = MFMA(cs[t], av, accS[mt * 3 + t]);
            }
        }
    };
    auto compute_single_first = [&](const __bf16* As, int ks, const bf16x8* cw) {
        #pragma unroll
        for (int mt = 0; mt < 4; ++mt) {
            bf16x8 av = *(const bf16x8*)(As + (mt * 6 + ks) * 512 + l8);
            #pragma unroll
            for (int t = 0; t < 3; ++t)
                accT[mt * 3 + t] = MFMA(cw[t], av, fzero);
        }
    };
    auto compute_single = [&](const __bf16* As, int ks, const bf16x8* cw) {
        #pragma unroll
        for (int mt = 0; mt < 4; ++mt) {
            bf16x8 av = *(const bf16x8*)(As + (mt * 6 + ks) * 512 + l8);
            #pragma unroll
            for (int t = 0; t < 3; ++t)
                accT[mt * 3 + t] = MFMA(cw[t], av, accT[mt * 3 + t]);
        }
    };
    // store 12 f32x4 (C-layout) into dst frag-major as bf16
    auto store_fragmajor = [&](__bf16* dst, const f32x4* src) {
        #pragma unroll
        for (int t = 0; t < 3; ++t) {
            int ks2 = (3 * wv + t) >> 1;                       // (48wv+16t)>>5
            int qp  = (6 * wv + 2 * t + (quad >> 1)) & 3;      // chunk within frag
            int off = (qp * 16 + ln) * 8 + (quad & 1) * 4;     // 8B-aligned
            #pragma unroll
            for (int mt = 0; mt < 4; ++mt) {
                bf16x4 o;
                #pragma unroll
                for (int rg = 0; rg < 4; ++rg) o[rg] = (__bf16)src[mt * 3 + t][rg];
                *(bf16x4*)(dst + (mt * 6 + ks2) * 512 + off) = o;
            }
        }
    };
    // h2f = gelu(accT + bias) + accS + sbias   (packed 2-wide; order = legacy)
    auto ep_skip = [&](const float* bias, const float* sbias) {
        #pragma unroll
        for (int t = 0; t < 3; ++t) {
            int colb = c0 + t * 16 + quad * 4;
            f32x4 bb = *(const f32x4*)(bias  + aH + colb);
            f32x4 sb = *(const f32x4*)(sbias + aH + colb);
            f32x2 bbl = lo2(bb), bbh = hi2(bb), sbl = lo2(sb), sbh = hi2(sb);
            #pragma unroll
            for (int mt = 0; mt < 4; ++mt) {
                int i = mt * 3 + t;
                f32x2 g0 = gelu2(lo2(accT[i]) + bbl);
                f32x2 g1 = gelu2(hi2(accT[i]) + bbh);
                f32x2 h0 = (g0 + lo2(accS[i])) + sbl;
                f32x2 h1 = (g1 + hi2(accS[i])) + sbh;
                h2f[i] = cmb(h0, h1);
            }
        }
    };

    __syncthreads();                                   // B1: x_norm (bufA) ready

    // ================= layer1 + skip1 (K=64, 2 chunks) =================
    {
        bf16x8 cw[3], cs[3];
        #pragma unroll
        for (int t = 0; t < 3; ++t) { cw[t] = nxt[t]; cs[t] = nxt[3 + t]; }
        #pragma unroll
        for (int t = 0; t < 3; ++t) {                  // prefetch L1 ks1
            nxt[t]     = *(const bf16x8*)(W1 + ((f3 + t) * 2 + 1) * 512 + l8);
            nxt[3 + t] = *(const bf16x8*)(S1 + ((f3 + t) * 2 + 1) * 512 + l8);
        }
        compute_dual_first(bufA, 2, 0, cw, cs);
        #pragma unroll
        for (int t = 0; t < 3; ++t) { cw[t] = nxt[t]; cs[t] = nxt[3 + t]; }
        #pragma unroll
        for (int t = 0; t < 3; ++t) {                  // prefetch L2 ks0
            nxt[t]     = *(const bf16x8*)(W2 + ((f3 + t) * 6 + 0) * 512 + l8);
            nxt[3 + t] = *(const bf16x8*)(S2 + ((f3 + t) * 6 + 0) * 512 + l8);
        }
        compute_dual(bufA, 2, 1, cw, cs);
    }
    ep_skip(b1, s1b);                                  // h1 (fp32) in h2f
    store_fragmajor(bufB, h2f);
    __syncthreads();                                   // B2: h1 (bufB) ready

    // ================= layer2 + skip2 (K=192, 6 chunks) =================
    #pragma unroll
    for (int ks = 0; ks < 6; ++ks) {
        bf16x8 cw[3], cs[3];
        #pragma unroll
        for (int t = 0; t < 3; ++t) { cw[t] = nxt[t]; cs[t] = nxt[3 + t]; }
        if (ks < 5) {
            #pragma unroll
            for (int t = 0; t < 3; ++t) {
                nxt[t]     = *(const bf16x8*)(W2 + ((f3 + t) * 6 + ks + 1) * 512 + l8);
                nxt[3 + t] = *(const bf16x8*)(S2 + ((f3 + t) * 6 + ks + 1) * 512 + l8);
            }
        } else {
            #pragma unroll
            for (int t = 0; t < 3; ++t)                // prefetch L3 ks0
                nxt[t] = *(const bf16x8*)(W3 + ((f3 + t) * 6 + 0) * 512 + l8);
        }
        if (ks == 0) compute_dual_first(bufB, 6, ks, cw, cs);
        else         compute_dual(bufB, 6, ks, cw, cs);
    }
    ep_skip(b2, s2b);                                  // h2 (fp32) in h2f, kept for residual
    // h2 -> bufA (x_norm reads all finished before B2; no extra barrier needed)
    store_fragmajor(bufA, h2f);
    __syncthreads();                                   // B3: h2 (bufA) ready

    // ================= layer3 (K=192) =================
    bf16x8 ow6[6];
    #pragma unroll
    for (int ks = 0; ks < 6; ++ks) {
        bf16x8 cw[3];
        #pragma unroll
        for (int t = 0; t < 3; ++t) cw[t] = nxt[t];
        if (ks < 5) {
            #pragma unroll
            for (int t = 0; t < 3; ++t)
                nxt[t] = *(const bf16x8*)(W3 + ((f3 + t) * 6 + ks + 1) * 512 + l8);
        } else {
            #pragma unroll
            for (int kk = 0; kk < 6; ++kk)             // prefetch OW
                ow6[kk] = *(const bf16x8*)(OWp + kk * 512 + l8);
        }
        if (ks == 0) compute_single_first(bufA, ks, cw);
        else         compute_single(bufA, ks, cw);
    }
    // h3 = (accT + b3 + h2)*hnw + hnb   (packed 2-wide; order = legacy)
    #pragma unroll
    for (int t = 0; t < 3; ++t) {
        int colb = c0 + t * 16 + quad * 4;
        f32x4 b3v = *(const f32x4*)(b3  + aH + colb);
        f32x4 nwv = *(const f32x4*)(hnw + aH + colb);
        f32x4 nbv = *(const f32x4*)(hnb + aH + colb);
        #pragma unroll
        for (int mt = 0; mt < 4; ++mt) {
            int i = mt * 3 + t;
            f32x2 s0 = (lo2(accT[i]) + lo2(b3v)) + lo2(h2f[i]);
            f32x2 s1 = (hi2(accT[i]) + hi2(b3v)) + hi2(h2f[i]);
            h2f[i] = cmb(fma2(s0, lo2(nwv), lo2(nbv)),
                         fma2(s1, hi2(nwv), hi2(nbv)));
        }
    }
    // h3 -> bufB (h1 reads all finished before B3; no extra barrier needed)
    store_fragmajor(bufB, h2f);
    __syncthreads();                                   // B4: h3 (bufB) ready

    // ================= output (wave wv = row-mtile wv) =================
    {
        f32x4 acco = fzero;
        #pragma unroll
        for (int ks = 0; ks < 6; ++ks) {
            bf16x8 av = *(const bf16x8*)(bufB + (wv * 6 + ks) * 512 + l8);
            acco = MFMA(ow6[ks], av, acco);
        }
        if (quad == 0) {                               // o = rg (0..2), rows = wv*16+ln
            float* po = out + ((size_t)a * B_N + row0 + wv * 16 + ln) * O_N;
            po[0] = acco[0] + ob[a * O_N + 0];
            po[1] = acco[1] + ob[a * O_N + 1];
            po[2] = acco[2] + ob[a * O_N + 2];
        }
    }
}

extern "C" void kernel_launch(void* const* d_in, const int* in_sizes, int n_in,
                              void* d_out, int out_size, void* d_ws, size_t ws_size,
                              hipStream_t stream) {
    const float* x   = (const float*)d_in[0];
    const float* inw = (const float*)d_in[1];
    const float* inb = (const float*)d_in[2];
    const float* w1  = (const float*)d_in[3];
    const float* b1  = (const float*)d_in[4];
    const float* w2  = (const float*)d_in[5];
    const float* b2  = (const float*)d_in[6];
    const float* w3  = (const float*)d_in[7];
    const float* b3  = (const float*)d_in[8];
    const float* ow  = (const float*)d_in[9];
    const float* ob  = (const float*)d_in[10];
    const float* s1w = (const float*)d_in[11];
    const float* s1b = (const float*)d_in[12];
    const float* s2w = (const float*)d_in[13];
    const float* s2b = (const float*)d_in[14];
    const float* hnw = (const float*)d_in[15];
    const float* hnb = (const float*)d_in[16];

    __bf16* ws = (__bf16*)d_ws;   // 17.7 MB of d_ws

    prep_kernel<<<dim3(1292), dim3(256), 0, stream>>>(w1, s1w, w2, s2w, w3, ow, ws);

    srek_mfma<<<dim3(A_N * (B_N / 64)), dim3(256), 0, stream>>>(
        x, inw, inb, b1, b2, b3, s1b, s2b, hnw, hnb, ob, ws, (float*)d_out);
}